// Round 3
// baseline (379.357 us; speedup 1.0000x reference)
//
#include <hip/hip_runtime.h>
#include <hip/hip_cooperative_groups.h>
#include <stdint.h>

namespace cg = cooperative_groups;

#define HIDDEN 1024
#define INTER  4096
#define ROWS   8192               // 4 * 2048
#define NBLK   256                // 128 row-tiles x 2 column halves
#define BM     64                 // rows per block
#define BN     512                // cols per block (half of HIDDEN)
#define BK     64                 // i8 K-elems per step
#define NKSTEP 64                 // INTER / BK
#define BTILE  65536              // full 1024-col K-step B image (bytes)

typedef int i32x4 __attribute__((ext_vector_type(4)));
typedef const uint32_t __attribute__((address_space(1))) gu32;
typedef uint32_t __attribute__((address_space(3))) lu32;

// sign byte: +1 (0x01) for x>=0, -1 (0xFF) for x<0.
__device__ __forceinline__ uint32_t sgn4(float4 v) {
    uint32_t b0 = (v.x < 0.f) ? 0xFFu : 0x01u;
    uint32_t b1 = (v.y < 0.f) ? 0xFFu : 0x01u;
    uint32_t b2 = (v.z < 0.f) ? 0xFFu : 0x01u;
    uint32_t b3 = (v.w < 0.f) ? 0xFFu : 0x01u;
    return b0 | (b1 << 8) | (b2 << 16) | (b3 << 24);
}

// ---------------------------------------------------------------------------
// One cooperative kernel, 256 blocks x 512 threads (1 block/CU):
//   phase 0: pack W -> frag-major Bg + wscale (each block packs 4 W-rows)
//   grid.sync()
//   phase 1: i8 MFMA GEMM, BM=64 x BN=512, B wave-private w/ counted vmcnt
//   phase 2: bias+residual, per-row partial (s,q) -> sqws workspace
//   grid.sync()
//   phase 3: mu/rsqrt from both halves' partials, LN transform, store
// Bg frag-major layout (per round-2, HW-verified): byte(h,k) =
//   (k>>6)*BTILE + (h>>4)*1024 + ((k&63)>>4)*256 + (h&15)*16 + (k&15)
// ---------------------------------------------------------------------------
__global__ __launch_bounds__(512, 2)
void fused_kernel(const float* __restrict__ hs, const float* __restrict__ input,
                  const float* __restrict__ W, const float* __restrict__ bias,
                  const float* __restrict__ clipp, const float* __restrict__ gamma,
                  const float* __restrict__ beta, float* __restrict__ out,
                  uint8_t* __restrict__ Bg, float* __restrict__ wscale,
                  float2* __restrict__ sqws) {
    __shared__ alignas(16) uint8_t smem[131072 + 1024];
    uint8_t* sB   = smem;                          // K-loop: 2 x 32 KB B tiles
    uint8_t* sA   = smem + 65536;                  // K-loop: 2 x 4 KB A sign tiles
    float*   s_mu = (float*)(smem + 131072);       // 64
    float*   s_rs = (float*)(smem + 131072 + 256); // 64
    float*   redp = (float*)(smem + 131072 + 512); // pack-phase scratch

    const int tid  = threadIdx.x;
    const int lane = tid & 63;
    const int wave = tid >> 6;
    cg::grid_group grid = cg::this_grid();

    // ---------------- phase 0: pack W (4 rows per block) ----------------
    {
        const int h   = blockIdx.x * 4 + (tid >> 7);
        const int pos = tid & 127;
        const float4* row = (const float4*)(W + (size_t)h * INTER);
        const uint32_t base_h = (uint32_t)(h >> 4) * 1024u + (uint32_t)(h & 15) * 16u;
        float asum = 0.f;
        #pragma unroll
        for (int j = 0; j < 8; ++j) {
            int g = pos + j * 128;                 // float4 index 0..1023
            float4 v = row[g];
            asum += fabsf(v.x) + fabsf(v.y) + fabsf(v.z) + fabsf(v.w);
            uint32_t off = (uint32_t)(g >> 4) * (uint32_t)BTILE + base_h
                         + (uint32_t)((g & 15) >> 2) * 256u + (uint32_t)(g & 3) * 4u;
            *(uint32_t*)(Bg + off) = sgn4(v);
        }
        #pragma unroll
        for (int off = 32; off > 0; off >>= 1) asum += __shfl_down(asum, off);
        if (lane == 0) redp[wave] = asum;
        __syncthreads();
        if (tid < 4)
            wscale[blockIdx.x * 4 + tid] = (redp[2 * tid] + redp[2 * tid + 1]) * (1.0f / INTER);
    }
    grid.sync();

    // ---------------- phase 1: GEMM ----------------
    const int m0 = (blockIdx.x >> 1) * BM;
    const int ch = blockIdx.x & 1;                 // column half (0 or 1)

    // A staging: thread (r = tid>>3, c8 = tid&7) loads 8 floats of row r.
    const int r  = tid >> 3;
    const int c8 = tid & 7;
    const int awofs = (r >> 4) * 1024 + ((c8 >> 1) * 16 + (r & 15)) * 16 + (c8 & 1) * 8;
    const float4* aload = (const float4*)(hs + (size_t)(m0 + r) * INTER + c8 * 8);
    // step t: aload[t*16], aload[t*16+1]

    // B: wave w owns cols ch*512 + w*64 .. +64 (wave-private region, 4 KB/step)
    const uint8_t* bsrc = Bg + (ch * 32 + wave * 4) * 1024 + lane * 16;
    uint8_t* bdst = sB + wave * 4096;
    const int fofs = lane * 16;

    i32x4 acc[4][4];
    #pragma unroll
    for (int rt = 0; rt < 4; ++rt)
        #pragma unroll
        for (int cf = 0; cf < 4; ++cf) acc[rt][cf] = (i32x4){0, 0, 0, 0};

    // prologue: A(0),B(0),A(1),B(1); commit sA[0]
    float4 avA0 = aload[0], avA1 = aload[1];
    #pragma unroll
    for (int j = 0; j < 4; ++j)
        __builtin_amdgcn_global_load_lds((gu32*)(bsrc + j * 1024),
                                         (lu32*)(bdst + j * 1024), 16, 0, 0);
    float4 avB0 = aload[16], avB1 = aload[17];
    #pragma unroll
    for (int j = 0; j < 4; ++j)
        __builtin_amdgcn_global_load_lds((gu32*)(bsrc + BTILE + j * 1024),
                                         (lu32*)(bdst + 32768 + j * 1024), 16, 0, 0);
    *(uint32_t*)&sA[awofs]     = sgn4(avA0);
    *(uint32_t*)&sA[awofs + 4] = sgn4(avA1);
    asm volatile("s_waitcnt lgkmcnt(0)" ::: "memory");
    __builtin_amdgcn_s_barrier();

// One K-step. vmcnt(6) keeps next tile's {2 A-loads + 4 B-loads} in flight.
#define GEMM_BODY(T, CUR, DO_WRITE, DO_ISSUE, VM, AW0, AW1, AL0, AL1) do {    \
    asm volatile("s_waitcnt vmcnt(" #VM ")" ::: "memory");                    \
    const uint8_t* bb_ = sB + (CUR) * 32768 + wave * 4096;                    \
    const uint8_t* ab_ = sA + (CUR) * 4096;                                   \
    i32x4 af0_ = *(const i32x4*)&ab_[fofs];                                   \
    i32x4 af1_ = *(const i32x4*)&ab_[1024 + fofs];                            \
    i32x4 af2_ = *(const i32x4*)&ab_[2048 + fofs];                            \
    i32x4 af3_ = *(const i32x4*)&ab_[3072 + fofs];                            \
    _Pragma("unroll")                                                         \
    for (int cf_ = 0; cf_ < 4; ++cf_) {                                       \
        i32x4 bf_ = *(const i32x4*)&bb_[cf_ * 1024 + fofs];                   \
        acc[0][cf_] = __builtin_amdgcn_mfma_i32_16x16x64_i8(af0_, bf_, acc[0][cf_], 0, 0, 0); \
        acc[1][cf_] = __builtin_amdgcn_mfma_i32_16x16x64_i8(af1_, bf_, acc[1][cf_], 0, 0, 0); \
        acc[2][cf_] = __builtin_amdgcn_mfma_i32_16x16x64_i8(af2_, bf_, acc[2][cf_], 0, 0, 0); \
        acc[3][cf_] = __builtin_amdgcn_mfma_i32_16x16x64_i8(af3_, bf_, acc[3][cf_], 0, 0, 0); \
    }                                                                         \
    if (DO_WRITE) {                                                           \
        *(uint32_t*)&sA[((CUR) ^ 1) * 4096 + awofs]     = sgn4(AW0);          \
        *(uint32_t*)&sA[((CUR) ^ 1) * 4096 + awofs + 4] = sgn4(AW1);          \
    }                                                                         \
    asm volatile("s_waitcnt lgkmcnt(0)" ::: "memory");                        \
    if (DO_ISSUE) {                                                           \
        AL0 = aload[((T) + 2) * 16];                                          \
        AL1 = aload[((T) + 2) * 16 + 1];                                      \
        _Pragma("unroll")                                                     \
        for (int j_ = 0; j_ < 4; ++j_)                                        \
            __builtin_amdgcn_global_load_lds(                                 \
                (gu32*)(bsrc + (size_t)((T) + 2) * BTILE + j_ * 1024),        \
                (lu32*)(bdst + (CUR) * 32768 + j_ * 1024), 16, 0, 0);         \
    }                                                                         \
    __builtin_amdgcn_s_barrier();                                             \
} while (0)

    for (int tt = 0; tt < 31; ++tt) {
        const int t0 = 2 * tt;
        GEMM_BODY(t0,     0, 1, 1, 6, avB0, avB1, avA0, avA1);
        GEMM_BODY(t0 + 1, 1, 1, 1, 6, avA0, avA1, avB0, avB1);
    }
    GEMM_BODY(62, 0, 1, 0, 6, avB0, avB1, avA0, avA1);  // write A(63), no issue
    GEMM_BODY(63, 1, 0, 0, 0, avA0, avA1, avB0, avB1);  // final: drain
#undef GEMM_BODY

    __syncthreads();

    // ---------------- phase 2: bias + residual + partial stats ----------------
    const float clip = clipp[0];
    const int l15 = lane & 15;
    const int rq  = (lane >> 4) * 4;
    float cw[4], bi[4];
    #pragma unroll
    for (int cf = 0; cf < 4; ++cf) {
        int gcol = ch * BN + wave * 64 + cf * 16 + l15;
        cw[cf] = clip * wscale[gcol];
        bi[cf] = bias[gcol];
    }

    // scatter y = cw*dot + bias into LDS (sB/sA dead)
    float* yl = (float*)smem;                      // [64][512]
    #pragma unroll
    for (int rt = 0; rt < 4; ++rt)
        #pragma unroll
        for (int cf = 0; cf < 4; ++cf)
            #pragma unroll
            for (int rg = 0; rg < 4; ++rg) {
                int rw = rt * 16 + rq + rg;
                int cl = wave * 64 + cf * 16 + l15;
                yl[rw * BN + cl] = fmaf((float)acc[rt][cf][rg], cw[cf], bi[cf]);
            }
    __syncthreads();

    // region-linear (1 KB per wave-instr): residual add + per-row (s,q)
    float4* yl4 = (float4*)yl;
    const float4* in4 = (const float4*)input;
    float s8[8], q8[8];
    #pragma unroll
    for (int j = 0; j < 8; ++j) { s8[j] = 0.f; q8[j] = 0.f; }
    #pragma unroll
    for (int j = 0; j < 16; ++j) {
        int g   = wave * 16 + j;
        int idx = g * 64 + lane;                   // f4 index in yl
        int rw  = idx >> 7;                        // = wave*8 + (j>>1)
        float4 y4 = yl4[idx];
        float4 r4 = in4[(size_t)(m0 + rw) * 256 + ch * 128 + (idx & 127)];
        y4.x += r4.x; y4.y += r4.y; y4.z += r4.z; y4.w += r4.w;
        yl4[idx] = y4;
        s8[j >> 1] += y4.x + y4.y + y4.z + y4.w;
        q8[j >> 1] += y4.x * y4.x + y4.y * y4.y + y4.z * y4.z + y4.w * y4.w;
    }
    #pragma unroll
    for (int off = 1; off < 64; off <<= 1)
        #pragma unroll
        for (int j = 0; j < 8; ++j) {
            s8[j] += __shfl_xor(s8[j], off);
            q8[j] += __shfl_xor(q8[j], off);
        }
    if (lane == 0) {
        #pragma unroll
        for (int j = 0; j < 8; ++j)
            sqws[(size_t)(m0 + wave * 8 + j) * 2 + ch] = make_float2(s8[j], q8[j]);
    }

    grid.sync();

    // ---------------- phase 3: LayerNorm finish ----------------
    if (tid < BM) {
        float2 p0 = sqws[(size_t)(m0 + tid) * 2 + 0];
        float2 p1 = sqws[(size_t)(m0 + tid) * 2 + 1];
        float s = p0.x + p1.x, q = p0.y + p1.y;
        float mu  = s * (1.0f / HIDDEN);
        float var = fmaf(-mu, mu, q * (1.0f / HIDDEN));
        s_mu[tid] = mu;
        s_rs[tid] = rsqrtf(var + 1e-12f);
    }
    __syncthreads();

    const float4* gm4 = (const float4*)gamma;
    const float4* bt4 = (const float4*)beta;
    float4 g0 = gm4[ch * 128 + lane], g1 = gm4[ch * 128 + 64 + lane];
    float4 b0 = bt4[ch * 128 + lane], b1 = bt4[ch * 128 + 64 + lane];
    float4* out4 = (float4*)out;
    #pragma unroll
    for (int j = 0; j < 16; ++j) {
        int g   = wave * 16 + j;
        int idx = g * 64 + lane;
        int rw  = idx >> 7;
        float4 y4 = yl4[idx];
        float4 gg = (j & 1) ? g1 : g0;
        float4 bb = (j & 1) ? b1 : b0;
        float mu = s_mu[rw], rs = s_rs[rw];
        float4 o;
        o.x = (y4.x - mu) * rs * gg.x + bb.x;
        o.y = (y4.y - mu) * rs * gg.y + bb.y;
        o.z = (y4.z - mu) * rs * gg.z + bb.z;
        o.w = (y4.w - mu) * rs * gg.w + bb.w;
        out4[(size_t)(m0 + rw) * 256 + ch * 128 + (idx & 127)] = o;
    }
}

// ---------------------------------------------------------------------------
extern "C" void kernel_launch(void* const* d_in, const int* in_sizes, int n_in,
                              void* d_out, int out_size, void* d_ws, size_t ws_size,
                              hipStream_t stream) {
    const float* hs    = (const float*)d_in[0];  // [4,2048,4096]
    const float* inp   = (const float*)d_in[1];  // [4,2048,1024]
    const float* W     = (const float*)d_in[2];  // [1024,4096]
    const float* b     = (const float*)d_in[3];  // [1024]
    const float* clip  = (const float*)d_in[4];  // scalar
    const float* gamma = (const float*)d_in[5];  // [1024]
    const float* beta  = (const float*)d_in[6];  // [1024]
    float* out = (float*)d_out;

    uint8_t* Bg   = (uint8_t*)d_ws;                                   // 4 MB
    float* wscale = (float*)((char*)d_ws + 4u * 1024u * 1024u);       // 4 KB
    float2* sqws  = (float2*)((char*)d_ws + 4u * 1024u * 1024u + 4096u); // 128 KB

    void* args[] = { (void*)&hs, (void*)&inp, (void*)&W, (void*)&b, (void*)&clip,
                     (void*)&gamma, (void*)&beta, (void*)&out,
                     (void*)&Bg, (void*)&wscale, (void*)&sqws };
    hipLaunchCooperativeKernel((const void*)fused_kernel, dim3(NBLK), dim3(512),
                               args, 0, stream);
}

// Round 5
// 298.296 us; speedup vs baseline: 1.2717x; 1.2717x over previous
//
#include <hip/hip_runtime.h>
#include <stdint.h>

#define HIDDEN 1024
#define INTER  4096
#define ROWS   8192               // 4 * 2048
#define BM     32                 // rows per GEMM block
#define BN     512                // cols per GEMM block (half of HIDDEN)
#define NKSTEP 64                 // INTER / 64
#define NBLK   512                // 256 row-tiles x 2 column halves
#define BSTEP  65536              // bytes per K-step in Bg (full 1024 cols)

typedef int i32x4 __attribute__((ext_vector_type(4)));

// sign byte: +1 (0x01) for x>=0, -1 (0xFF) for x<0.
__device__ __forceinline__ uint32_t sgn4(float4 v) {
    uint32_t b0 = (v.x < 0.f) ? 0xFFu : 0x01u;
    uint32_t b1 = (v.y < 0.f) ? 0xFFu : 0x01u;
    uint32_t b2 = (v.z < 0.f) ? 0xFFu : 0x01u;
    uint32_t b3 = (v.w < 0.f) ? 0xFFu : 0x01u;
    return b0 | (b1 << 8) | (b2 << 16) | (b3 << 24);
}

// ---------------------------------------------------------------------------
// K1: W [1024][4096] f32 -> Bg frag-major i8 signs + wscale (r2-proven layout):
//   byte(h,k) = (k>>6)*BSTEP + (h>>4)*1024 + ((k&63)>>4)*256 + (h&15)*16 + (k&15)
// A 16-col MFMA B-fragment for K-step t is the contiguous 1 KB at
//   Bg + t*BSTEP + cb*1024, element lane*16.
// ---------------------------------------------------------------------------
__global__ __launch_bounds__(256)
void pack_w_kernel(const float* __restrict__ W, uint8_t* __restrict__ Bg,
                   float* __restrict__ wscale) {
    int h = blockIdx.x;
    int tid = threadIdx.x;
    int lane = tid & 63, wv = tid >> 6;
    const float4* row = (const float4*)(W + (size_t)h * INTER);
    const uint32_t base_h = (uint32_t)(h >> 4) * 1024u + (uint32_t)(h & 15) * 16u;
    float asum = 0.f;
    #pragma unroll
    for (int q = 0; q < 4; ++q) {
        int g = q * 256 + tid;                 // float4 index 0..1023 (coalesced)
        float4 v = row[g];
        asum += fabsf(v.x) + fabsf(v.y) + fabsf(v.z) + fabsf(v.w);
        uint32_t off = (uint32_t)(g >> 4) * (uint32_t)BSTEP + base_h
                     + (uint32_t)((g & 15) >> 2) * 256u + (uint32_t)(g & 3) * 4u;
        *(uint32_t*)(Bg + off) = sgn4(v);
    }
    #pragma unroll
    for (int off = 32; off > 0; off >>= 1) asum += __shfl_down(asum, off);
    __shared__ float red[4];
    if (lane == 0) red[wv] = asum;
    __syncthreads();
    if (tid == 0) wscale[h] = (red[0] + red[1] + red[2] + red[3]) * (1.0f / INTER);
}

// ---------------------------------------------------------------------------
// K2: i8 MFMA GEMM, 512 blocks x 512 thr (plain launch, no co-residency dep).
//   bid -> (m = bid&255, ch = bid>>8); b and b+256 share bid%8 -> same XCD.
//   B wave-private, streamed global->VGPR 2-deep (compiler-counted waits, no
//   vmcnt drain, no B barrier). Only the shared 2KB A sign-tile uses LDS +
//   one raw s_barrier per K-step.
//   Epilogue: y = cw*dot + bias + input -> out (pre-LN), per-row-half (s,q)
//   partials -> sqws. LN finished by K3.
// LDS = 64KB y-stage + 4KB A = 68KB -> 2 blocks/CU target (not required).
// ---------------------------------------------------------------------------
__global__ __launch_bounds__(512, 4)
void gemm_kernel(const float* __restrict__ hs, const float* __restrict__ input,
                 const float* __restrict__ bias, const float* __restrict__ clipp,
                 float* __restrict__ out, const uint8_t* __restrict__ Bg,
                 const float* __restrict__ wscale, float2* __restrict__ sqws) {
    __shared__ alignas(16) uint8_t yls[65536];   // epilogue y[32][512] f32
    __shared__ alignas(16) uint8_t sA[2 * 2048]; // A sign tiles (frag-major)

    const int tid  = threadIdx.x;
    const int lane = tid & 63;
    const int wave = tid >> 6;
    const int mt   = blockIdx.x & 255;
    const int ch   = blockIdx.x >> 8;            // column half
    const int m0   = mt * BM;

    // A staging: thread (r = tid>>4, c4 = tid&15) loads one float4 of row r,
    // writes 4 sign bytes at the frag-major A address.
    const int r  = tid >> 4;
    const int c4 = tid & 15;
    const int awofs = (r >> 4) * 1024 + ((c4 >> 2) * 16 + (r & 15)) * 16 + (c4 & 3) * 4;
    const float* aload = hs + (size_t)(m0 + r) * INTER + c4 * 4;

    // B: wave w owns cols ch*512 + w*64 .. +63; 4 contiguous-1KB frag loads.
    const uint8_t* bbase = Bg + (size_t)(ch * 32 + wave * 4) * 1024 + lane * 16;
    const int fofs = lane * 16;

    i32x4 acc[2][4];
    #pragma unroll
    for (int rt = 0; rt < 2; ++rt)
        #pragma unroll
        for (int cf = 0; cf < 4; ++cf) acc[rt][cf] = (i32x4){0, 0, 0, 0};
    i32x4 Bb0[4], Bb1[4];

    // ---- prologue: A(0) staged, B(0) in regs, A(1) data pending ----
    float4 avA = *(const float4*)aload;
    #pragma unroll
    for (int cf = 0; cf < 4; ++cf) Bb0[cf] = *(const i32x4*)(bbase + cf * 1024);
    *(uint32_t*)&sA[awofs] = sgn4(avA);
    avA = *(const float4*)(aload + 64);
    asm volatile("s_waitcnt lgkmcnt(0)" ::: "memory");
    __builtin_amdgcn_s_barrier();

// Body T: compute tile T from Bb<BC> + sA[CUR]; prefetch B(T+1) into Bb<BN_>
// (plain register loads -> compiler emits exact counted vmcnt and lets them
// stay in flight across the barrier); stage A(T+1); load A(T+2) data.
#define BODY(T, CUR, BC, BN_, PFB, PFA) do {                                   \
    i32x4 af0_ = *(const i32x4*)&sA[(CUR) * 2048 + fofs];                      \
    i32x4 af1_ = *(const i32x4*)&sA[(CUR) * 2048 + 1024 + fofs];               \
    if (PFB) {                                                                 \
        const uint8_t* bp_ = bbase + (size_t)((T) + 1) * BSTEP;                \
        _Pragma("unroll")                                                      \
        for (int cf_ = 0; cf_ < 4; ++cf_)                                      \
            Bb##BN_[cf_] = *(const i32x4*)(bp_ + cf_ * 1024);                  \
    }                                                                          \
    __builtin_amdgcn_s_setprio(1);                                             \
    _Pragma("unroll")                                                          \
    for (int cf_ = 0; cf_ < 4; ++cf_) {                                        \
        acc[0][cf_] = __builtin_amdgcn_mfma_i32_16x16x64_i8(af0_, Bb##BC[cf_], acc[0][cf_], 0, 0, 0); \
        acc[1][cf_] = __builtin_amdgcn_mfma_i32_16x16x64_i8(af1_, Bb##BC[cf_], acc[1][cf_], 0, 0, 0); \
    }                                                                          \
    __builtin_amdgcn_s_setprio(0);                                             \
    if (PFB) {                                                                 \
        *(uint32_t*)&sA[((CUR) ^ 1) * 2048 + awofs] = sgn4(avA);               \
        if (PFA) avA = *(const float4*)(aload + ((T) + 2) * 64);               \
        asm volatile("s_waitcnt lgkmcnt(0)" ::: "memory");                     \
        __builtin_amdgcn_s_barrier();                                          \
    }                                                                          \
} while (0)

    for (int tt = 0; tt < 31; ++tt) {
        BODY(2 * tt,     0, 0, 1, 1, 1);
        BODY(2 * tt + 1, 1, 1, 0, 1, 1);
    }
    BODY(62, 0, 0, 1, 1, 0);   // prefetch B(63), stage A(63); no A(64) load
    BODY(63, 1, 1, 0, 0, 0);   // final tile
#undef BODY

    // ---- epilogue: y = clip*wscale*dot + bias -> LDS stage ----
    const float clip = clipp[0];
    const int l15 = lane & 15;
    const int g4i = lane >> 4;
    float cw[4], bi[4];
    #pragma unroll
    for (int cf = 0; cf < 4; ++cf) {
        int gcol = ch * BN + wave * 64 + cf * 16 + l15;
        cw[cf] = clip * wscale[gcol];
        bi[cf] = bias[gcol];
    }
    float* yl = (float*)yls;                    // [32][512]
    #pragma unroll
    for (int rt = 0; rt < 2; ++rt)
        #pragma unroll
        for (int cf = 0; cf < 4; ++cf)
            #pragma unroll
            for (int rg = 0; rg < 4; ++rg) {
                int rw = rt * 16 + g4i * 4 + rg;
                int cl = wave * 64 + cf * 16 + l15;
                yl[rw * BN + cl] = fmaf((float)acc[rt][cf][rg], cw[cf], bi[cf]);
            }
    __syncthreads();

    // residual add + coalesced store of pre-LN y + per-row-half (s,q)
    float4* yl4 = (float4*)yl;
    const float4* in4 = (const float4*)input;
    float4* out4 = (float4*)out;
    float s = 0.f, q = 0.f;
    #pragma unroll
    for (int j = 0; j < 8; ++j) {
        int idx  = r * 128 + c4 + j * 16;                    // f4 index in yl
        int gidx = (int)((size_t)0) + c4 + j * 16;           // col f4 in half
        float4 y4 = yl4[idx];
        float4 r4 = in4[(size_t)(m0 + r) * 256 + ch * 128 + gidx];
        y4.x += r4.x; y4.y += r4.y; y4.z += r4.z; y4.w += r4.w;
        out4[(size_t)(m0 + r) * 256 + ch * 128 + gidx] = y4;
        s += y4.x + y4.y + y4.z + y4.w;
        q += y4.x * y4.x + y4.y * y4.y + y4.z * y4.z + y4.w * y4.w;
    }
    #pragma unroll
    for (int off = 1; off <= 8; off <<= 1) {
        s += __shfl_xor(s, off);
        q += __shfl_xor(q, off);
    }
    if (c4 == 0) sqws[(size_t)(m0 + r) * 2 + ch] = make_float2(s, q);
}

// ---------------------------------------------------------------------------
// K3: in-place LayerNorm finish. 2048 blocks x 256 thr; one row per wave.
// ---------------------------------------------------------------------------
__global__ __launch_bounds__(256)
void ln_kernel(float* __restrict__ out, const float2* __restrict__ sqws,
               const float* __restrict__ gamma, const float* __restrict__ beta) {
    const int lane = threadIdx.x & 63;
    const int wave = threadIdx.x >> 6;
    const int row  = blockIdx.x * 4 + wave;
    float2 p0 = sqws[(size_t)row * 2 + 0];
    float2 p1 = sqws[(size_t)row * 2 + 1];
    float ss = p0.x + p1.x, qq = p0.y + p1.y;
    float mu  = ss * (1.0f / HIDDEN);
    float var = fmaf(-mu, mu, qq * (1.0f / HIDDEN));
    float rs  = rsqrtf(var + 1e-12f);
    float4* rowp = (float4*)(out + (size_t)row * HIDDEN);
    const float4* gm4 = (const float4*)gamma;
    const float4* bt4 = (const float4*)beta;
    #pragma unroll
    for (int j = 0; j < 4; ++j) {
        int idx = lane + j * 64;
        float4 y = rowp[idx];
        float4 g = gm4[idx], b = bt4[idx];
        float4 o;
        o.x = (y.x - mu) * rs * g.x + b.x;
        o.y = (y.y - mu) * rs * g.y + b.y;
        o.z = (y.z - mu) * rs * g.z + b.z;
        o.w = (y.w - mu) * rs * g.w + b.w;
        rowp[idx] = o;
    }
}

// ---------------------------------------------------------------------------
extern "C" void kernel_launch(void* const* d_in, const int* in_sizes, int n_in,
                              void* d_out, int out_size, void* d_ws, size_t ws_size,
                              hipStream_t stream) {
    const float* hs    = (const float*)d_in[0];  // [4,2048,4096]
    const float* inp   = (const float*)d_in[1];  // [4,2048,1024]
    const float* W     = (const float*)d_in[2];  // [1024,4096]
    const float* b     = (const float*)d_in[3];  // [1024]
    const float* clip  = (const float*)d_in[4];  // scalar
    const float* gamma = (const float*)d_in[5];  // [1024]
    const float* beta  = (const float*)d_in[6];  // [1024]
    float* out = (float*)d_out;

    uint8_t* Bg   = (uint8_t*)d_ws;                                      // 4 MB
    float* wscale = (float*)((char*)d_ws + 4u * 1024u * 1024u);          // 4 KB
    float2* sqws  = (float2*)((char*)d_ws + 4u * 1024u * 1024u + 4096u); // 128 KB

    pack_w_kernel<<<HIDDEN, 256, 0, stream>>>(W, Bg, wscale);
    gemm_kernel<<<NBLK, 512, 0, stream>>>(hs, inp, b, clip, out, Bg, wscale, sqws);
    ln_kernel<<<ROWS / 4, 256, 0, stream>>>(out, sqws, gamma, beta);
}